// Round 15
// baseline (545.279 us; speedup 1.0000x reference)
//
#include <hip/hip_runtime.h>
#include <cstdint>
#include <cstddef>

#define E_N 500000
#define FD 128
#define TD 100
#define OD 128
#define NT 4
#define IND 228   // FD + TD
#define KP 256    // K padded to MFMA multiple
#define GRID1 1024

// workspace: only the converted W
static constexpr size_t WS_NEED = (size_t)NT * OD * KP * 2;   // 262,144 B

typedef __attribute__((ext_vector_type(8))) short short8;
typedef __attribute__((ext_vector_type(4))) float f32x4;

__device__ __forceinline__ unsigned short f2bf(float x) {
  union { float f; unsigned u; } v; v.f = x;
  unsigned r = v.u + 0x7fff + ((v.u >> 16) & 1);   // RNE, inputs are finite
  return (unsigned short)(r >> 16);
}

// swizzled byte offset into the A tile: row r (0..63), k elem (0..255), bf16.
__device__ __forceinline__ int a_off(int r, int k) {
  return ((r << 9) + (k << 1)) ^ ((r & 7) << 4);
}

// W [NT][IND][OD] f32 -> Wbf [NT][OD][KP] bf16 (N-major, K zero-padded beyond 228)
__global__ void wconv_kernel(const float* __restrict__ W, unsigned short* __restrict__ Wbf) {
  int row = blockIdx.x * 4 + (threadIdx.x >> 6);   // row = t*OD + n, 0..511
  int t = row >> 7, n = row & 127;
  int k0 = (threadIdx.x & 63) << 2;
  ushort4 o;
  float v0 = (k0 + 0 < IND) ? W[((size_t)t * IND + k0 + 0) * OD + n] : 0.f;
  float v1 = (k0 + 1 < IND) ? W[((size_t)t * IND + k0 + 1) * OD + n] : 0.f;
  float v2 = (k0 + 2 < IND) ? W[((size_t)t * IND + k0 + 2) * OD + n] : 0.f;
  float v3 = (k0 + 3 < IND) ? W[((size_t)t * IND + k0 + 3) * OD + n] : 0.f;
  o.x = f2bf(v0); o.y = f2bf(v1); o.z = f2bf(v2); o.w = f2bf(v3);
  *(ushort4*)(Wbf + ((size_t)row << 8) + k0) = o;
}

// Main kernel: stream 64-edge tiles in original order (sequential feats read +
// out write -> clean HBM). Per tile, wave 0 stable-sorts rows by type (ballot
// prefix, no padding); staging WRITES THROUGH the permutation so MFMA reads
// consecutive rows (2-way banks = free). Boundary subtiles run one pass per
// distinct type with per-lane store predication. Waves own 64 cols x pass
// parity. bf16 packing via f2bf ONLY -- the v_cvt_pk_bf16_f32 inline asm
// produced absmax ~0.85 failures in r3/r14 (r4..r13 with f2bf all passed).
__global__ __launch_bounds__(256) void gemm_kernel(
    const float* __restrict__ feats, const float* __restrict__ ts,
    const int* __restrict__ types, const float* __restrict__ freqs,
    const float* __restrict__ b, const float* __restrict__ temb,
    const unsigned short* __restrict__ Wbf, float* __restrict__ out) {
  __shared__ __align__(16) char smA[64 * 512];      // A bf16 [64 slots][256], XOR-swizzled
  __shared__ __align__(16) float sfreq[NT * 128];   // per-type freqs, zero-padded
  __shared__ __align__(16) float sbias[NT * 128];   // b + temb
  __shared__ int pos2[2][64];    // row -> slot
  __shared__ int org2[2][64];    // slot -> row (local)
  __shared__ int styp2[2][64];   // slot -> type (99 = invalid)
  __shared__ int plist2[2][16];  // (subtile<<2)|type
  __shared__ int npass2[2];

  const int ntiles = (E_N + 63) >> 6;
  const int chunk = (ntiles + GRID1 - 1) / GRID1;
  const int t0 = blockIdx.x * chunk;
  const int t1 = min(t0 + chunk, ntiles);
  if (t0 >= t1) return;

  const int tid = threadIdx.x;
  const int w = tid >> 6, lane = tid & 63;
  const int bl = lane & 15, bh = lane >> 4;
  const int r = tid >> 2, part = tid & 3;   // 4 threads per row; part = 32-elem window
  const int cg = w & 1, pp = w >> 1;        // col-half (64 cols), pass parity

  for (int i = tid; i < NT * 128; i += 256) {
    int ty = i >> 7, d = i & 127;
    sfreq[i] = (d < TD) ? freqs[ty * TD + d] : 0.f;
    sbias[i] = b[i] + temb[i];
  }

  // wave 0: stable sort rows by type; build boundary-aware pass list
  auto compact = [&](int buf, int tile) {
    if (tid >= 64) return;
    int e = tile * 64 + tid;
    int tr = (e < E_N) ? types[e] : 99;
    const unsigned long long lt = (1ull << tid) - 1ull;
    int bases[5]; int slot = -1; int base = 0;
    #pragma unroll
    for (int q = 0; q < 4; ++q) {
      unsigned long long m = __ballot(tr == q);
      bases[q] = base;
      if (tr == q) slot = base + (int)__popcll(m & lt);
      base += (int)__popcll(m);
    }
    bases[4] = base;
    {
      unsigned long long m = __ballot(tr == 99);
      if (tr == 99) slot = base + (int)__popcll(m & lt);
    }
    pos2[buf][tid] = slot;
    org2[buf][slot] = tid;
    styp2[buf][slot] = tr;
    if (tid == 0) {
      int np = 0;
      for (int s = 0; s < 4; ++s)
        for (int q = 0; q < 4; ++q) {
          int lo = bases[q], hi = bases[q + 1];
          if (lo < hi && lo < (s + 1) * 16 && hi > s * 16) plist2[buf][np++] = (s << 2) | q;
        }
      npass2[buf] = np;
    }
  };

  // stage this thread's 32 feats + 32 time elems of row r into slot pos2[buf][r]
  auto stage = [&](int buf, const float4* p, float tvv, int trr, bool valid) {
    if (!valid) return;
    const int drow = pos2[buf][r];
    union { unsigned short s[32]; uint4 v4[4]; } pk;
    union { unsigned short s[32]; uint4 v4[4]; } tk;
    #pragma unroll
    for (int c = 0; c < 8; ++c) {
      pk.s[4 * c + 0] = f2bf(p[c].x); pk.s[4 * c + 1] = f2bf(p[c].y);
      pk.s[4 * c + 2] = f2bf(p[c].z); pk.s[4 * c + 3] = f2bf(p[c].w);
    }
    #pragma unroll
    for (int m = 0; m < 8; ++m) {
      float4 fq = *(const float4*)&sfreq[trr * 128 + part * 32 + 4 * m];
      tk.s[4 * m + 0] = f2bf(__cosf(tvv * fq.x));
      tk.s[4 * m + 1] = f2bf(__cosf(tvv * fq.y));
      tk.s[4 * m + 2] = f2bf(__cosf(tvv * fq.z));
      tk.s[4 * m + 3] = f2bf(__cosf(tvv * fq.w));
    }
    #pragma unroll
    for (int j = 0; j < 4; ++j)
      *(uint4*)(smA + a_off(drow, part * 32 + 8 * j)) = pk.v4[j];
    #pragma unroll
    for (int j = 0; j < 4; ++j)
      *(uint4*)(smA + a_off(drow, FD + part * 32 + 8 * j)) = tk.v4[j];
  };

  // ---- prologue: tile t0 ----
  float4 pf[8];
  float tv = 0.f; int trr = 0; bool vld = false;
  {
    int e = t0 * 64 + r;
    vld = (e < E_N);
    if (vld) {
      tv = ts[e]; trr = types[e];
      const float4* src = (const float4*)(feats + (size_t)e * FD + part * 32);
      #pragma unroll
      for (int c = 0; c < 8; ++c) pf[c] = src[c];
    }
  }
  compact(0, t0);
  __syncthreads();                 // sfreq/sbias + pos2[0] ready
  stage(0, pf, tv, trr, vld);

  for (int tt = t0; tt < t1; ++tt) {
    const int cur = (tt - t0) & 1, nxt = cur ^ 1;
    const bool last = (tt == t1 - 1);
    __syncthreads();               // A(tt) + meta(cur) ready

    // streaming prefetch of tile tt+1 + next tile's sort (rides under MFMA)
    float tvb = 0.f; int trb = 0; bool vb = false;
    if (!last) {
      int e = (tt + 1) * 64 + r;
      vb = (e < E_N);
      if (vb) {
        tvb = ts[e]; trb = types[e];
        const float4* src = (const float4*)(feats + (size_t)e * FD + part * 32);
        #pragma unroll
        for (int c = 0; c < 8; ++c) pf[c] = src[c];
      }
      compact(nxt, tt + 1);
    }

    // ---- passes: type-uniform 16-row subtile x this wave's 64 cols ----
    const int np = npass2[cur];
    for (int p = pp; p < np; p += 2) {
      const int sq = plist2[cur][p];
      const int s = sq >> 2, q = sq & 3;
      const int sl = s * 16 + bl;
      short8 av[8];
      #pragma unroll
      for (int k = 0; k < 8; ++k)
        av[k] = *(const short8*)(smA + a_off(sl, k * 32 + bh * 8));
      const float* bb_ = &sbias[q * 128 + cg * 64 + bh * 4];
      f32x4 a0 = *(const f32x4*)(bb_);
      f32x4 a1 = *(const f32x4*)(bb_ + 16);
      f32x4 a2 = *(const f32x4*)(bb_ + 32);
      f32x4 a3 = *(const f32x4*)(bb_ + 48);
      const unsigned short* wp = Wbf + (((size_t)q * OD + cg * 64 + bl) << 8) + (bh << 3);
      __builtin_amdgcn_s_setprio(1);
      #pragma unroll
      for (int k = 0; k < 8; ++k) {
        a0 = __builtin_amdgcn_mfma_f32_16x16x32_bf16(*(const short8*)(wp + 0 * 4096 + k * 32), av[k], a0, 0, 0, 0);
        a1 = __builtin_amdgcn_mfma_f32_16x16x32_bf16(*(const short8*)(wp + 1 * 4096 + k * 32), av[k], a1, 0, 0, 0);
        a2 = __builtin_amdgcn_mfma_f32_16x16x32_bf16(*(const short8*)(wp + 2 * 4096 + k * 32), av[k], a2, 0, 0, 0);
        a3 = __builtin_amdgcn_mfma_f32_16x16x32_bf16(*(const short8*)(wp + 3 * 4096 + k * 32), av[k], a3, 0, 0, 0);
      }
      __builtin_amdgcn_s_setprio(0);
      if (styp2[cur][sl] == q) {     // each valid row stored exactly once
        const int orow = tt * 64 + org2[cur][sl];
        float* dst = out + (size_t)orow * OD + cg * 64 + bh * 4;
        *(f32x4*)(dst)      = a0;
        *(f32x4*)(dst + 16) = a1;
        *(f32x4*)(dst + 32) = a2;
        *(f32x4*)(dst + 48) = a3;
      }
    }
    __syncthreads();               // A consumed; meta(nxt) published

    if (!last) {
      stage(nxt, pf, tvb, trb, vb);
      tv = tvb; trr = trb; vld = vb;
    }
  }
}

// correctness fallback if ws is too small (fp32 vector path)
__global__ void naive_kernel(const float* __restrict__ feats, const float* __restrict__ ts,
                             const int* __restrict__ types, const float* __restrict__ W,
                             const float* __restrict__ b, const float* __restrict__ temb,
                             const float* __restrict__ freqs, float* __restrict__ out) {
  __shared__ float comb[IND];
  int e = blockIdx.x;
  int t = types[e];
  int tid = threadIdx.x;  // 128 threads
  comb[tid] = feats[(size_t)e * FD + tid];
  if (tid < TD) comb[FD + tid] = __cosf(ts[e] * freqs[t * TD + tid]);
  __syncthreads();
  float acc = b[t * OD + tid] + temb[t * OD + tid];
  for (int k = 0; k < IND; ++k) acc += comb[k] * W[((size_t)t * IND + k) * OD + tid];
  out[(size_t)e * OD + tid] = acc;
}

extern "C" void kernel_launch(void* const* d_in, const int* in_sizes, int n_in,
                              void* d_out, int out_size, void* d_ws, size_t ws_size,
                              hipStream_t stream) {
  const float* feats = (const float*)d_in[0];
  const float* ts    = (const float*)d_in[1];
  const int*   types = (const int*)d_in[2];
  const float* W     = (const float*)d_in[3];
  const float* bb    = (const float*)d_in[4];
  const float* temb  = (const float*)d_in[5];
  const float* freqs = (const float*)d_in[6];
  float* out = (float*)d_out;

  if (ws_size < WS_NEED) {
    naive_kernel<<<E_N, 128, 0, stream>>>(feats, ts, types, W, bb, temb, freqs, out);
    return;
  }

  unsigned short* Wbf = (unsigned short*)d_ws;
  wconv_kernel<<<(NT * OD) / 4, 256, 0, stream>>>(W, Wbf);
  gemm_kernel<<<GRID1, 256, 0, stream>>>(feats, ts, types, freqs, bb, temb, Wbf, out);
}

// Round 16
// 178.741 us; speedup vs baseline: 3.0507x; 3.0507x over previous
//
#include <hip/hip_runtime.h>
#include <cstdint>
#include <cstddef>

#define E_N 500000
#define FD 128
#define TD 100
#define OD 128
#define NT 4
#define IND 228   // FD + TD
#define KP 256    // K padded to MFMA multiple
#define GX 256    // chunks per type for gemm
#define NB 1954   // ceil(E_N/256) histogram blocks
#define EPS 136   // epilogue LDS row stride in floats

// workspace layout (bytes)
static constexpr size_t BUCKET_OFF = 0;                                   // int[E_N]
static constexpr size_t WBF_OFF    = 2000000;                             // bf16[NT][OD][KP]
static constexpr size_t BIASC_OFF  = WBF_OFF + (size_t)NT * OD * KP * 2;  // float[NT][OD]
static constexpr size_t CTR_OFF    = BIASC_OFF + (size_t)NT * OD * 4;     // int[16]
static constexpr size_t PART_OFF   = CTR_OFF + 64;                        // int[NB*4]
static constexpr size_t BBASE_OFF  = PART_OFF + (size_t)NB * 4 * 4;       // int[NB*4]
static constexpr size_t WS_NEED    = BBASE_OFF + (size_t)NB * 4 * 4;

typedef __attribute__((ext_vector_type(8))) short short8;
typedef __attribute__((ext_vector_type(4))) float f32x4;

__device__ __forceinline__ unsigned short f2bf(float x) {
  union { float f; unsigned u; } v; v.f = x;
  unsigned r = v.u + 0x7fff + ((v.u >> 16) & 1);   // RNE, inputs are finite
  return (unsigned short)(r >> 16);
}

// swizzled byte offset into the A tile: row r (0..63), k elem (0..255), bf16.
__device__ __forceinline__ int a_off(int r, int k) {
  return ((r << 9) + (k << 1)) ^ ((r & 7) << 4);
}

// epilogue LDS word offset: row (edge 0..63), slot (16B chunk 0..31 of the row)
__device__ __forceinline__ int ep_w(int row, int slot) {
  return row * EPS + ((slot ^ (row & 7)) << 2);
}

// per-block type histogram (1 edge/thread, ballot counts, no atomics)
__global__ void hist_kernel(const int* __restrict__ types, int* __restrict__ partial, int n) {
  __shared__ int wcnt[4][NT];
  const int tid = threadIdx.x, w = tid >> 6, l = tid & 63;
  const int i = blockIdx.x * 256 + tid;
  const int t = (i < n) ? types[i] : -1;
  #pragma unroll
  for (int q = 0; q < NT; ++q) {
    unsigned long long m = __ballot(t == q);
    if (l == 0) wcnt[w][q] = (int)__popcll(m);
  }
  __syncthreads();
  if (tid < NT) {
    int s = 0;
    #pragma unroll
    for (int w2 = 0; w2 < 4; ++w2) s += wcnt[w2][tid];
    partial[blockIdx.x * NT + tid] = s;
  }
}

// single block: exclusive scan of per-block counts -> blockbase; type totals ->
// ctr[0..3]=counts, ctr[4..7]=offsets. Fused bias precompute. Deterministic.
__global__ void scan_kernel(const int* __restrict__ partial, int* __restrict__ blockbase,
                            int* __restrict__ ctr, const float* __restrict__ b,
                            const float* __restrict__ temb, float* __restrict__ biasc) {
  __shared__ int4 tsum[256];
  const int tid = threadIdx.x;
  int4 s = make_int4(0, 0, 0, 0);
  #pragma unroll
  for (int j = 0; j < 8; ++j) {
    int blk = tid * 8 + j;
    if (blk < NB) {
      const int* p = partial + blk * 4;
      s.x += p[0]; s.y += p[1]; s.z += p[2]; s.w += p[3];
    }
  }
  tsum[tid] = s;
  __syncthreads();
  if (tid == 0) {
    int4 run = make_int4(0, 0, 0, 0);
    for (int i = 0; i < 256; ++i) {
      int4 v = tsum[i]; tsum[i] = run;
      run.x += v.x; run.y += v.y; run.z += v.z; run.w += v.w;
    }
    ctr[0] = run.x; ctr[1] = run.y; ctr[2] = run.z; ctr[3] = run.w;
    int off = 0;
    ctr[4] = 0;            off += run.x;
    ctr[5] = off;          off += run.y;
    ctr[6] = off;          off += run.z;
    ctr[7] = off;
  }
  __syncthreads();
  int4 run = tsum[tid];
  #pragma unroll
  for (int j = 0; j < 8; ++j) {
    int blk = tid * 8 + j;
    if (blk < NB) {
      const int* p = partial + blk * 4;
      int* bb = blockbase + blk * 4;
      bb[0] = run.x; bb[1] = run.y; bb[2] = run.z; bb[3] = run.w;
      run.x += p[0]; run.y += p[1]; run.z += p[2]; run.w += p[3];
    }
  }
  for (int i = tid; i < NT * OD; i += 256) biasc[i] = b[i] + temb[i];
}

// W [NT][IND][OD] f32 -> Wbf [NT][OD][KP] bf16 (N-major, K zero-padded beyond 228)
__global__ void wconv_kernel(const float* __restrict__ W, unsigned short* __restrict__ Wbf) {
  int row = blockIdx.x * 4 + (threadIdx.x >> 6);   // row = t*OD + n, 0..511
  int t = row >> 7, n = row & 127;
  int k0 = (threadIdx.x & 63) << 2;
  ushort4 o;
  float v0 = (k0 + 0 < IND) ? W[((size_t)t * IND + k0 + 0) * OD + n] : 0.f;
  float v1 = (k0 + 1 < IND) ? W[((size_t)t * IND + k0 + 1) * OD + n] : 0.f;
  float v2 = (k0 + 2 < IND) ? W[((size_t)t * IND + k0 + 2) * OD + n] : 0.f;
  float v3 = (k0 + 3 < IND) ? W[((size_t)t * IND + k0 + 3) * OD + n] : 0.f;
  o.x = f2bf(v0); o.y = f2bf(v1); o.z = f2bf(v2); o.w = f2bf(v3);
  *(ushort4*)(Wbf + ((size_t)row << 8) + k0) = o;
}

// deterministic SORTED fill: pos = type_off + blockbase[b][t] + in-block rank.
// bucket[] per type is ascending by edge index -> tile gathers/scatters are
// ascending strided rows; with co-dispatched type-blocks they union into a
// dense sequential DRAM stream.
__global__ void fill_kernel(const int* __restrict__ types, const int* __restrict__ blockbase,
                            const int* __restrict__ ctr, int* __restrict__ bucket, int n) {
  __shared__ int wcnt[4][NT];
  __shared__ int wbase[4][NT];
  const int tid = threadIdx.x, w = tid >> 6, l = tid & 63;
  const int i = blockIdx.x * 256 + tid;
  const int t = (i < n) ? types[i] : -1;
  unsigned long long m[NT];
  #pragma unroll
  for (int q = 0; q < NT; ++q) {
    m[q] = __ballot(t == q);
    if (l == 0) wcnt[w][q] = (int)__popcll(m[q]);
  }
  __syncthreads();
  if (tid < NT) {
    int q = tid, s = 0;
    #pragma unroll
    for (int w2 = 0; w2 < 4; ++w2) { wbase[w2][q] = s; s += wcnt[w2][q]; }
  }
  __syncthreads();
  if (t >= 0) {
    int rank = wbase[w][t] + (int)__popcll(m[t] & ((1ull << l) - 1ull));
    bucket[ctr[4 + t] + blockbase[blockIdx.x * 4 + t] + rank] = i;
  }
}

// Main kernel: r9 verbatim (proven 170us, clean traffic) except blockIdx
// mapping: x=type, y=chunk -> the 4 types' blocks over the same edge region
// dispatch consecutively and union their ascending strided gathers into a
// dense sequential stream.
__global__ __launch_bounds__(256) void gemm_kernel(
    const float* __restrict__ feats, const float* __restrict__ ts,
    const float* __restrict__ freqs, const unsigned short* __restrict__ Wbf,
    const float* __restrict__ biasc, const int* __restrict__ bucket,
    const int* __restrict__ ctr, float* __restrict__ out) {
  __shared__ __align__(16) char smraw[64 * EPS * 4];
  __shared__ __align__(16) float sfreq[128];

  const int t = blockIdx.x;
  const int cnt = ctr[t];
  const int off = ctr[4 + t];
  const int ntiles = (cnt + 63) >> 6;
  const int chunk = (ntiles + GX - 1) / GX;
  const int t0 = blockIdx.y * chunk;
  const int t1 = min(t0 + chunk, ntiles);
  if (t0 >= t1) return;

  const int tid = threadIdx.x;
  const int wid = tid >> 6, lane = tid & 63;
  const int bl = lane & 15, bh = lane >> 4;
  const int r = tid >> 2, part = tid & 3;   // 4 threads per A-row; part = 32-elem window

  // W fragments, first MFMA operand (A-layout): lane bl <-> out-col, k-window bh*8
  short8 bfrag[8][2];
  #pragma unroll
  for (int n = 0; n < 2; ++n) {
    const unsigned short* bp =
        Wbf + (((size_t)t * OD + wid * 32 + n * 16 + bl) << 8) + (bh << 3);
    #pragma unroll
    for (int k = 0; k < 8; ++k) bfrag[k][n] = *(const short8*)(bp + k * 32);
  }
  // bias for this lane's cols: col = wid*32 + n*16 + bh*4 + j
  const float4 bv0 = *(const float4*)(biasc + t * OD + wid * 32 + bh * 4);
  const float4 bv1 = *(const float4*)(biasc + t * OD + wid * 32 + 16 + bh * 4);

  if (tid < 128) sfreq[tid] = (tid < TD) ? freqs[t * TD + tid] : 0.f;

  auto stage = [&](const float4* p, float tvv) {
    union { unsigned short s[32]; uint4 v4[4]; } pk;
    union { unsigned short s[32]; uint4 v4[4]; } tk;
    #pragma unroll
    for (int c = 0; c < 8; ++c) {
      pk.s[4 * c + 0] = f2bf(p[c].x); pk.s[4 * c + 1] = f2bf(p[c].y);
      pk.s[4 * c + 2] = f2bf(p[c].z); pk.s[4 * c + 3] = f2bf(p[c].w);
    }
    #pragma unroll
    for (int m = 0; m < 8; ++m) {
      float4 fq = *(const float4*)&sfreq[part * 32 + 4 * m];
      tk.s[4 * m + 0] = f2bf(__cosf(tvv * fq.x));
      tk.s[4 * m + 1] = f2bf(__cosf(tvv * fq.y));
      tk.s[4 * m + 2] = f2bf(__cosf(tvv * fq.z));
      tk.s[4 * m + 3] = f2bf(__cosf(tvv * fq.w));
    }
    #pragma unroll
    for (int j = 0; j < 4; ++j)
      *(uint4*)(smraw + a_off(r, part * 32 + 8 * j)) = pk.v4[j];
    #pragma unroll
    for (int j = 0; j < 4; ++j)
      *(uint4*)(smraw + a_off(r, FD + part * 32 + 8 * j)) = tk.v4[j];
  };

  // ---- prologue ----
  int e_cur = -1; float tv_cur = 0.f;
  {
    const int va = min(64, cnt - t0 * 64);
    if (r < va) { e_cur = bucket[off + t0 * 64 + r]; tv_cur = ts[e_cur]; }
  }
  float4 pf[8];
  if (e_cur >= 0) {
    const float4* src = (const float4*)(feats + (size_t)e_cur * FD + part * 32);
    #pragma unroll
    for (int c = 0; c < 8; ++c) pf[c] = src[c];
  }
  int e_b = -1; float tv_b = 0.f;
  if (t0 + 1 < t1) {
    const int vb = min(64, cnt - (t0 + 1) * 64);
    if (r < vb) { e_b = bucket[off + (t0 + 1) * 64 + r]; tv_b = ts[e_b]; }
  }
  __syncthreads();                    // sfreq visible
  if (e_cur >= 0) stage(pf, tv_cur);

  for (int tt = t0; tt < t1; ++tt) {
    const bool last = (tt == t1 - 1);
    __syncthreads();   // A(tt) ready

    if (!last && e_b >= 0) {
      const float4* src = (const float4*)(feats + (size_t)e_b * FD + part * 32);
      #pragma unroll
      for (int c = 0; c < 8; ++c) pf[c] = src[c];
    }
    int e_c = -1; float tv_c = 0.f;
    if (tt + 2 < t1) {
      const int vc = min(64, cnt - (tt + 2) * 64);
      if (r < vc) { e_c = bucket[off + (tt + 2) * 64 + r]; tv_c = ts[e_c]; }
    }

    // ---- MFMA, bias in acc-init ----
    f32x4 acc[4][2];
    #pragma unroll
    for (int rt = 0; rt < 4; ++rt) {
      acc[rt][0][0] = bv0.x; acc[rt][0][1] = bv0.y; acc[rt][0][2] = bv0.z; acc[rt][0][3] = bv0.w;
      acc[rt][1][0] = bv1.x; acc[rt][1][1] = bv1.y; acc[rt][1][2] = bv1.z; acc[rt][1][3] = bv1.w;
    }
    __builtin_amdgcn_s_setprio(1);
    #pragma unroll
    for (int rt = 0; rt < 4; ++rt) {
      #pragma unroll
      for (int k = 0; k < 8; ++k) {
        short8 av = *(const short8*)(smraw + a_off(rt * 16 + bl, k * 32 + bh * 8));
        acc[rt][0] = __builtin_amdgcn_mfma_f32_16x16x32_bf16(bfrag[k][0], av, acc[rt][0], 0, 0, 0);
        acc[rt][1] = __builtin_amdgcn_mfma_f32_16x16x32_bf16(bfrag[k][1], av, acc[rt][1], 0, 0, 0);
      }
    }
    __builtin_amdgcn_s_setprio(0);
    __syncthreads();   // A reads done; region reusable

    // ---- epilogue write: lane -> row rt*16+bl, slot wid*8+{0,4}+bh ----
    float* ep = (float*)smraw;
    #pragma unroll
    for (int rt = 0; rt < 4; ++rt) {
      *(f32x4*)(ep + ep_w(rt * 16 + bl, wid * 8 + 0 + bh)) = acc[rt][0];
      *(f32x4*)(ep + ep_w(rt * 16 + bl, wid * 8 + 4 + bh)) = acc[rt][1];
    }
    __syncthreads();   // epilogue visible

    // ---- store: thread owns its row's cols part*32..+31 (full-line pattern) ----
    if (e_cur >= 0) {
      float* dst = out + (size_t)e_cur * OD + part * 32;
      #pragma unroll
      for (int c = 0; c < 8; ++c) {
        f32x4 v = *(const f32x4*)(ep + ep_w(r, part * 8 + c));
        *(f32x4*)(dst + 4 * c) = v;
      }
    }

    if (!last) {
      __syncthreads();   // ep reads done before next stage overwrites
      if (e_b >= 0) stage(pf, tv_b);
      e_cur = e_b; tv_cur = tv_b;
      e_b = e_c; tv_b = tv_c;
    }
  }
}

// correctness fallback if ws is too small (fp32 vector path)
__global__ void naive_kernel(const float* __restrict__ feats, const float* __restrict__ ts,
                             const int* __restrict__ types, const float* __restrict__ W,
                             const float* __restrict__ b, const float* __restrict__ temb,
                             const float* __restrict__ freqs, float* __restrict__ out) {
  __shared__ float comb[IND];
  int e = blockIdx.x;
  int t = types[e];
  int tid = threadIdx.x;  // 128 threads
  comb[tid] = feats[(size_t)e * FD + tid];
  if (tid < TD) comb[FD + tid] = __cosf(ts[e] * freqs[t * TD + tid]);
  __syncthreads();
  float acc = b[t * OD + tid] + temb[t * OD + tid];
  for (int k = 0; k < IND; ++k) acc += comb[k] * W[((size_t)t * IND + k) * OD + tid];
  out[(size_t)e * OD + tid] = acc;
}

extern "C" void kernel_launch(void* const* d_in, const int* in_sizes, int n_in,
                              void* d_out, int out_size, void* d_ws, size_t ws_size,
                              hipStream_t stream) {
  const float* feats = (const float*)d_in[0];
  const float* ts    = (const float*)d_in[1];
  const int*   types = (const int*)d_in[2];
  const float* W     = (const float*)d_in[3];
  const float* bb    = (const float*)d_in[4];
  const float* temb  = (const float*)d_in[5];
  const float* freqs = (const float*)d_in[6];
  float* out = (float*)d_out;

  if (ws_size < WS_NEED) {
    naive_kernel<<<E_N, 128, 0, stream>>>(feats, ts, types, W, bb, temb, freqs, out);
    return;
  }

  char* ws = (char*)d_ws;
  int* bucket = (int*)(ws + BUCKET_OFF);
  unsigned short* Wbf = (unsigned short*)(ws + WBF_OFF);
  float* biasc = (float*)(ws + BIASC_OFF);
  int* ctr = (int*)(ws + CTR_OFF);
  int* partial = (int*)(ws + PART_OFF);
  int* blockbase = (int*)(ws + BBASE_OFF);

  hist_kernel<<<NB, 256, 0, stream>>>(types, partial, E_N);
  scan_kernel<<<1, 256, 0, stream>>>(partial, blockbase, ctr, bb, temb, biasc);
  wconv_kernel<<<(NT * OD) / 4, 256, 0, stream>>>(W, Wbf);
  fill_kernel<<<NB, 256, 0, stream>>>(types, blockbase, ctr, bucket, E_N);
  dim3 g(NT, GX);
  gemm_kernel<<<g, 256, 0, stream>>>(feats, ts, freqs, Wbf, biasc, bucket, ctr, out);
}